// Round 2
// baseline (204.210 us; speedup 1.0000x reference)
//
#include <hip/hip_runtime.h>
#include <math.h>

constexpr int kN = 4096;
constexpr int kD = 4;
constexpr int kTJ = 512;               // j-tile staged in LDS
constexpr int kBlock = 256;
constexpr int kWaves = kBlock / 64;    // 4 waves, 1 row each
constexpr int kRowsPerBlock = kWaves;  // 4

__global__ __launch_bounds__(kBlock, 8)
void kuramoto_kernel(const float* __restrict__ theta,
                     const float* __restrict__ gam,
                     const float* __restrict__ W,
                     const float* __restrict__ alpha,
                     float* __restrict__ out)
{
    // Transposed tables [d][j]: lane L reads float4 at byte offset L*16 ->
    // consecutive addresses, conflict-free ds_read_b128.
    __shared__ __align__(16) float sS[kD][kTJ];
    __shared__ __align__(16) float sC[kD][kTJ];

    const int tid  = threadIdx.x;
    const int wave = tid >> 6;
    const int lane = tid & 63;

    const int row  = blockIdx.x * kRowsPerBlock + wave;   // global row = b*N + i
    const int b    = (blockIdx.x * kRowsPerBlock) / kN;   // same b for whole block
    const float* thetaB = theta + (size_t)b * kN * kD;

    const float* __restrict__ Wrow = W     + (size_t)row * kN;
    const float* __restrict__ Arow = alpha + (size_t)row * kN;

    float U[kD] = {0.f, 0.f, 0.f, 0.f};
    float V[kD] = {0.f, 0.f, 0.f, 0.f};

    for (int j0 = 0; j0 < kN; j0 += kTJ) {
        __syncthreads();   // previous tile's LDS reads done before overwrite
        // Stage sin/cos(theta[b, j0:j0+kTJ, :]) transposed into LDS.
        #pragma unroll
        for (int k = 0; k < kTJ / kBlock; ++k) {          // 2 iterations
            const int jj = tid + k * kBlock;
            const float4 t4 = *reinterpret_cast<const float4*>(&thetaB[(size_t)(j0 + jj) * kD]);
            float s, c;
            __sincosf(t4.x, &s, &c); sS[0][jj] = s; sC[0][jj] = c;
            __sincosf(t4.y, &s, &c); sS[1][jj] = s; sC[1][jj] = c;
            __sincosf(t4.z, &s, &c); sS[2][jj] = s; sC[2][jj] = c;
            __sincosf(t4.w, &s, &c); sS[3][jj] = s; sC[3][jj] = c;
        }
        __syncthreads();

        // Each lane processes 4 consecutive j per iteration (float4 loads).
        #pragma unroll
        for (int it = 0; it < kTJ / (64 * 4); ++it) {     // 2 iterations
            const int jj = it * 256 + lane * 4;
            const float4 w4 = *reinterpret_cast<const float4*>(&Wrow[j0 + jj]);
            const float4 a4 = *reinterpret_cast<const float4*>(&Arow[j0 + jj]);
            float P[4], Q[4];
            float sa, ca;
            __sincosf(a4.x, &sa, &ca); P[0] = w4.x * ca; Q[0] = w4.x * sa;
            __sincosf(a4.y, &sa, &ca); P[1] = w4.y * ca; Q[1] = w4.y * sa;
            __sincosf(a4.z, &sa, &ca); P[2] = w4.z * ca; Q[2] = w4.z * sa;
            __sincosf(a4.w, &sa, &ca); P[3] = w4.w * ca; Q[3] = w4.w * sa;
            #pragma unroll
            for (int d = 0; d < kD; ++d) {
                const float4 s4 = *reinterpret_cast<const float4*>(&sS[d][jj]);
                const float4 c4 = *reinterpret_cast<const float4*>(&sC[d][jj]);
                U[d] = fmaf(P[0], s4.x, fmaf(-Q[0], c4.x, U[d]));
                V[d] = fmaf(P[0], c4.x, fmaf( Q[0], s4.x, V[d]));
                U[d] = fmaf(P[1], s4.y, fmaf(-Q[1], c4.y, U[d]));
                V[d] = fmaf(P[1], c4.y, fmaf( Q[1], s4.y, V[d]));
                U[d] = fmaf(P[2], s4.z, fmaf(-Q[2], c4.z, U[d]));
                V[d] = fmaf(P[2], c4.z, fmaf( Q[2], s4.z, V[d]));
                U[d] = fmaf(P[3], s4.w, fmaf(-Q[3], c4.w, U[d]));
                V[d] = fmaf(P[3], c4.w, fmaf( Q[3], s4.w, V[d]));
            }
        }
    }

    // Wave-wide butterfly reduction (8 accumulators per wave).
    #pragma unroll
    for (int m = 1; m < 64; m <<= 1) {
        #pragma unroll
        for (int d = 0; d < kD; ++d) {
            U[d] += __shfl_xor(U[d], m, 64);
            V[d] += __shfl_xor(V[d], m, 64);
        }
    }

    if (lane == 0) {
        const float4 t4 = *reinterpret_cast<const float4*>(&theta[(size_t)row * kD]);
        const float4 g4 = *reinterpret_cast<const float4*>(&gam[(size_t)row * kD]);
        const float tv[4] = {t4.x, t4.y, t4.z, t4.w};
        const float gv[4] = {g4.x, g4.y, g4.z, g4.w};
        constexpr float scale = 1.0f / (float)kN;        // GLOBAL_COUPLING / N
        float x[4];
        float nsq = 0.f;
        #pragma unroll
        for (int d = 0; d < kD; ++d) {
            float si, ci;
            __sincosf(tv[d], &si, &ci);
            const float coup = scale * (ci * U[d] - si * V[d]);
            x[d] = gv[d] + coup;        // gamma + coupling (drive cancels theta)
            nsq += x[d] * x[d];
        }
        const float inv = 1.0f / fmaxf(sqrtf(nsq), 1e-6f);
        float4 o;
        o.x = x[0] * inv; o.y = x[1] * inv; o.z = x[2] * inv; o.w = x[3] * inv;
        *reinterpret_cast<float4*>(&out[(size_t)row * kD]) = o;
    }
}

extern "C" void kernel_launch(void* const* d_in, const int* in_sizes, int n_in,
                              void* d_out, int out_size, void* d_ws, size_t ws_size,
                              hipStream_t stream) {
    const float* theta = (const float*)d_in[0];   // (B,N,D) f32
    const float* gam   = (const float*)d_in[1];   // (B,N,D) f32
    const float* W     = (const float*)d_in[2];   // (B,N,N) f32
    const float* alpha = (const float*)d_in[3];   // (B,N,N) f32
    float* out = (float*)d_out;                   // (B,N,D) f32

    const int totalRows = in_sizes[0] / kD;           // B*N = 8192
    const int nblocks = totalRows / kRowsPerBlock;    // 2048
    kuramoto_kernel<<<nblocks, kBlock, 0, stream>>>(theta, gam, W, alpha, out);
}

// Round 3
// 74.786 us; speedup vs baseline: 2.7306x; 2.7306x over previous
//
#include <hip/hip_runtime.h>
#include <math.h>

constexpr int kN = 4096;
constexpr int kD = 4;
constexpr int kB = 2;
constexpr int kTJ = 512;               // j-tile staged in LDS
constexpr int kBlock = 256;
constexpr int kWaves = kBlock / 64;    // 4 waves, 1 row each
constexpr int kRowsPerBlock = kWaves;  // 4

// Precompute sin/cos(theta) tables in transposed [b][d][j] layout.
__global__ __launch_bounds__(256)
void table_kernel(const float* __restrict__ theta,
                  float* __restrict__ sinT, float* __restrict__ cosT)
{
    const int idx = blockIdx.x * blockDim.x + threadIdx.x;   // over B*N*D
    const int d = idx & (kD - 1);
    const int j = (idx >> 2) & (kN - 1);
    const int b = idx >> 14;
    float s, c;
    __sincosf(theta[idx], &s, &c);
    const int t = (b * kD + d) * kN + j;
    sinT[t] = s;
    cosT[t] = c;
}

template <bool USE_TABLE>
__global__ __launch_bounds__(kBlock)
void kuramoto_kernel(const float* __restrict__ theta,
                     const float* __restrict__ gam,
                     const float* __restrict__ W,
                     const float* __restrict__ alpha,
                     const float* __restrict__ sinT,
                     const float* __restrict__ cosT,
                     float* __restrict__ out)
{
    // [d][j] layout: lane L reads float4 at byte offset L*32 (+16) ->
    // consecutive addresses, conflict-free ds_read_b128.
    __shared__ __align__(16) float sS[kD][kTJ];
    __shared__ __align__(16) float sC[kD][kTJ];

    const int tid  = threadIdx.x;
    const int wave = tid >> 6;
    const int lane = tid & 63;

    const int row  = blockIdx.x * kRowsPerBlock + wave;   // global row = b*N + i
    const int b    = (blockIdx.x * kRowsPerBlock) >> 12;  // same b for whole block

    const float* __restrict__ Wrow = W     + (size_t)row * kN;
    const float* __restrict__ Arow = alpha + (size_t)row * kN;

    float U[kD] = {0.f, 0.f, 0.f, 0.f};
    float V[kD] = {0.f, 0.f, 0.f, 0.f};

    for (int j0 = 0; j0 < kN; j0 += kTJ) {
        __syncthreads();   // previous tile's LDS reads done before overwrite
        if (USE_TABLE) {
            // Pure float4 copies from L2-resident tables (no trig).
            const float* __restrict__ sB = sinT + (size_t)b * kD * kN;
            const float* __restrict__ cB = cosT + (size_t)b * kD * kN;
            #pragma unroll
            for (int e4 = 0; e4 < 2; ++e4) {               // 512 float4 / 256 thr
                const int e = e4 * kBlock + tid;           // float4 index
                const int d  = e >> 7;                     // 128 float4 per d-row
                const int jj = (e & 127) * 4;
                *reinterpret_cast<float4*>(&sS[d][jj]) =
                    *reinterpret_cast<const float4*>(&sB[d * kN + j0 + jj]);
                *reinterpret_cast<float4*>(&sC[d][jj]) =
                    *reinterpret_cast<const float4*>(&cB[d * kN + j0 + jj]);
            }
        } else {
            const float* thetaB = theta + (size_t)b * kN * kD;
            #pragma unroll
            for (int k = 0; k < kTJ / kBlock; ++k) {
                const int jj = tid + k * kBlock;
                const float4 t4 = *reinterpret_cast<const float4*>(&thetaB[(size_t)(j0 + jj) * kD]);
                float s, c;
                __sincosf(t4.x, &s, &c); sS[0][jj] = s; sC[0][jj] = c;
                __sincosf(t4.y, &s, &c); sS[1][jj] = s; sC[1][jj] = c;
                __sincosf(t4.z, &s, &c); sS[2][jj] = s; sC[2][jj] = c;
                __sincosf(t4.w, &s, &c); sS[3][jj] = s; sC[3][jj] = c;
            }
        }
        __syncthreads();

        // Each lane processes 8 consecutive j per tile (2x float4 per stream).
        const int jj0 = lane * 8;
        const float4 w4a = *reinterpret_cast<const float4*>(&Wrow[j0 + jj0]);
        const float4 w4b = *reinterpret_cast<const float4*>(&Wrow[j0 + jj0 + 4]);
        const float4 a4a = *reinterpret_cast<const float4*>(&Arow[j0 + jj0]);
        const float4 a4b = *reinterpret_cast<const float4*>(&Arow[j0 + jj0 + 4]);
        float P[8], Q[8];
        {
            float sa, ca;
            __sincosf(a4a.x, &sa, &ca); P[0] = w4a.x * ca; Q[0] = w4a.x * sa;
            __sincosf(a4a.y, &sa, &ca); P[1] = w4a.y * ca; Q[1] = w4a.y * sa;
            __sincosf(a4a.z, &sa, &ca); P[2] = w4a.z * ca; Q[2] = w4a.z * sa;
            __sincosf(a4a.w, &sa, &ca); P[3] = w4a.w * ca; Q[3] = w4a.w * sa;
            __sincosf(a4b.x, &sa, &ca); P[4] = w4b.x * ca; Q[4] = w4b.x * sa;
            __sincosf(a4b.y, &sa, &ca); P[5] = w4b.y * ca; Q[5] = w4b.y * sa;
            __sincosf(a4b.z, &sa, &ca); P[6] = w4b.z * ca; Q[6] = w4b.z * sa;
            __sincosf(a4b.w, &sa, &ca); P[7] = w4b.w * ca; Q[7] = w4b.w * sa;
        }
        #pragma unroll
        for (int d = 0; d < kD; ++d) {
            const float4 s4a = *reinterpret_cast<const float4*>(&sS[d][jj0]);
            const float4 s4b = *reinterpret_cast<const float4*>(&sS[d][jj0 + 4]);
            const float4 c4a = *reinterpret_cast<const float4*>(&sC[d][jj0]);
            const float4 c4b = *reinterpret_cast<const float4*>(&sC[d][jj0 + 4]);
            const float sj[8] = {s4a.x, s4a.y, s4a.z, s4a.w, s4b.x, s4b.y, s4b.z, s4b.w};
            const float cj[8] = {c4a.x, c4a.y, c4a.z, c4a.w, c4b.x, c4b.y, c4b.z, c4b.w};
            #pragma unroll
            for (int q = 0; q < 8; ++q) {
                U[d] = fmaf(P[q], sj[q], fmaf(-Q[q], cj[q], U[d]));
                V[d] = fmaf(P[q], cj[q], fmaf( Q[q], sj[q], V[d]));
            }
        }
    }

    // Wave-wide butterfly reduction (8 accumulators per wave).
    #pragma unroll
    for (int m = 1; m < 64; m <<= 1) {
        #pragma unroll
        for (int d = 0; d < kD; ++d) {
            U[d] += __shfl_xor(U[d], m, 64);
            V[d] += __shfl_xor(V[d], m, 64);
        }
    }

    if (lane == 0) {
        const float4 t4 = *reinterpret_cast<const float4*>(&theta[(size_t)row * kD]);
        const float4 g4 = *reinterpret_cast<const float4*>(&gam[(size_t)row * kD]);
        const float tv[4] = {t4.x, t4.y, t4.z, t4.w};
        const float gv[4] = {g4.x, g4.y, g4.z, g4.w};
        constexpr float scale = 1.0f / (float)kN;        // GLOBAL_COUPLING / N
        float x[4];
        float nsq = 0.f;
        #pragma unroll
        for (int d = 0; d < kD; ++d) {
            float si, ci;
            __sincosf(tv[d], &si, &ci);
            const float coup = scale * (ci * U[d] - si * V[d]);
            x[d] = gv[d] + coup;        // gamma + coupling (drive cancels theta)
            nsq += x[d] * x[d];
        }
        const float inv = 1.0f / fmaxf(sqrtf(nsq), 1e-6f);
        float4 o;
        o.x = x[0] * inv; o.y = x[1] * inv; o.z = x[2] * inv; o.w = x[3] * inv;
        *reinterpret_cast<float4*>(&out[(size_t)row * kD]) = o;
    }
}

extern "C" void kernel_launch(void* const* d_in, const int* in_sizes, int n_in,
                              void* d_out, int out_size, void* d_ws, size_t ws_size,
                              hipStream_t stream) {
    const float* theta = (const float*)d_in[0];   // (B,N,D) f32
    const float* gam   = (const float*)d_in[1];   // (B,N,D) f32
    const float* W     = (const float*)d_in[2];   // (B,N,N) f32
    const float* alpha = (const float*)d_in[3];   // (B,N,N) f32
    float* out = (float*)d_out;                   // (B,N,D) f32

    const int totalRows = in_sizes[0] / kD;           // B*N = 8192
    const int nblocks = totalRows / kRowsPerBlock;    // 2048
    const size_t tabElems = (size_t)kB * kN * kD;     // 32768 per table
    const size_t needWs = 2 * tabElems * sizeof(float);

    if (ws_size >= needWs) {
        float* sinT = (float*)d_ws;
        float* cosT = sinT + tabElems;
        table_kernel<<<(int)(tabElems / 256), 256, 0, stream>>>(theta, sinT, cosT);
        kuramoto_kernel<true><<<nblocks, kBlock, 0, stream>>>(
            theta, gam, W, alpha, sinT, cosT, out);
    } else {
        kuramoto_kernel<false><<<nblocks, kBlock, 0, stream>>>(
            theta, gam, W, alpha, nullptr, nullptr, out);
    }
}

// Round 4
// 69.283 us; speedup vs baseline: 2.9475x; 1.0794x over previous
//
#include <hip/hip_runtime.h>
#include <math.h>

constexpr int kN = 4096;
constexpr int kD = 4;
constexpr int kB = 2;
constexpr int kBlock = 256;
constexpr int kWaves = kBlock / 64;    // 4 waves, 1 row each
constexpr int kRowsPerBlock = kWaves;  // 4
constexpr int kUnroll = 8;             // j's per lane per batch (MLP depth)

// Precompute sin/cos(theta) as float4-per-j tables: sinT[b*N+j] = {s_d0..s_d3}.
__global__ __launch_bounds__(256)
void table_kernel(const float* __restrict__ theta,
                  float4* __restrict__ sinT, float4* __restrict__ cosT)
{
    const int idx = blockIdx.x * blockDim.x + threadIdx.x;   // over B*N
    const float4 t4 = *reinterpret_cast<const float4*>(&theta[(size_t)idx * kD]);
    float4 s4, c4;
    __sincosf(t4.x, &s4.x, &c4.x);
    __sincosf(t4.y, &s4.y, &c4.y);
    __sincosf(t4.z, &s4.z, &c4.z);
    __sincosf(t4.w, &s4.w, &c4.w);
    sinT[idx] = s4;
    cosT[idx] = c4;
}

// Barrier-free streaming kernel: 1 row per wave, no LDS.
template <bool USE_TABLE>
__global__ __launch_bounds__(kBlock)
void kuramoto_kernel(const float* __restrict__ theta,
                     const float* __restrict__ gam,
                     const float* __restrict__ W,
                     const float* __restrict__ alpha,
                     const float4* __restrict__ sinT,
                     const float4* __restrict__ cosT,
                     float* __restrict__ out)
{
    const int tid  = threadIdx.x;
    const int wave = tid >> 6;
    const int lane = tid & 63;

    const int row = blockIdx.x * kRowsPerBlock + wave;    // global row = b*N + i
    const int b   = row >> 12;                            // row / kN

    const float* __restrict__ Wrow = W     + (size_t)row * kN;
    const float* __restrict__ Arow = alpha + (size_t)row * kN;
    const float4* __restrict__ sB = sinT + (size_t)b * kN;
    const float4* __restrict__ cB = cosT + (size_t)b * kN;
    const float* thetaB = theta + (size_t)b * kN * kD;

    float U[kD] = {0.f, 0.f, 0.f, 0.f};
    float V[kD] = {0.f, 0.f, 0.f, 0.f};

    // j = lane + 64*k, k = 0..63; batch kUnroll k's for load MLP.
    for (int k0 = 0; k0 < kN / 64; k0 += kUnroll) {
        float  w[kUnroll], a[kUnroll];
        float4 s4[kUnroll], c4[kUnroll];
        #pragma unroll
        for (int u = 0; u < kUnroll; ++u) {
            const int j = lane + (k0 + u) * 64;
            w[u] = Wrow[j];
            a[u] = Arow[j];
            if (USE_TABLE) {
                s4[u] = sB[j];          // 16B/lane, wave covers 1KB contiguous
                c4[u] = cB[j];
            } else {
                const float4 t4 = *reinterpret_cast<const float4*>(&thetaB[(size_t)j * kD]);
                __sincosf(t4.x, &s4[u].x, &c4[u].x);
                __sincosf(t4.y, &s4[u].y, &c4[u].y);
                __sincosf(t4.z, &s4[u].z, &c4[u].z);
                __sincosf(t4.w, &s4[u].w, &c4[u].w);
            }
        }
        #pragma unroll
        for (int u = 0; u < kUnroll; ++u) {
            float sa, ca;
            __sincosf(a[u], &sa, &ca);
            const float P = w[u] * ca;
            const float Q = w[u] * sa;
            U[0] = fmaf(P, s4[u].x, fmaf(-Q, c4[u].x, U[0]));
            V[0] = fmaf(P, c4[u].x, fmaf( Q, s4[u].x, V[0]));
            U[1] = fmaf(P, s4[u].y, fmaf(-Q, c4[u].y, U[1]));
            V[1] = fmaf(P, c4[u].y, fmaf( Q, s4[u].y, V[1]));
            U[2] = fmaf(P, s4[u].z, fmaf(-Q, c4[u].z, U[2]));
            V[2] = fmaf(P, c4[u].z, fmaf( Q, s4[u].z, V[2]));
            U[3] = fmaf(P, s4[u].w, fmaf(-Q, c4[u].w, U[3]));
            V[3] = fmaf(P, c4[u].w, fmaf( Q, s4[u].w, V[3]));
        }
    }

    // Wave-wide butterfly reduction (8 accumulators per wave).
    #pragma unroll
    for (int m = 1; m < 64; m <<= 1) {
        #pragma unroll
        for (int d = 0; d < kD; ++d) {
            U[d] += __shfl_xor(U[d], m, 64);
            V[d] += __shfl_xor(V[d], m, 64);
        }
    }

    if (lane == 0) {
        const float4 t4 = *reinterpret_cast<const float4*>(&theta[(size_t)row * kD]);
        const float4 g4 = *reinterpret_cast<const float4*>(&gam[(size_t)row * kD]);
        const float tv[4] = {t4.x, t4.y, t4.z, t4.w};
        const float gv[4] = {g4.x, g4.y, g4.z, g4.w};
        constexpr float scale = 1.0f / (float)kN;        // GLOBAL_COUPLING / N
        float x[4];
        float nsq = 0.f;
        #pragma unroll
        for (int d = 0; d < kD; ++d) {
            float si, ci;
            __sincosf(tv[d], &si, &ci);
            const float coup = scale * (ci * U[d] - si * V[d]);
            x[d] = gv[d] + coup;        // gamma + coupling (drive cancels theta)
            nsq += x[d] * x[d];
        }
        const float inv = 1.0f / fmaxf(sqrtf(nsq), 1e-6f);
        float4 o;
        o.x = x[0] * inv; o.y = x[1] * inv; o.z = x[2] * inv; o.w = x[3] * inv;
        *reinterpret_cast<float4*>(&out[(size_t)row * kD]) = o;
    }
}

extern "C" void kernel_launch(void* const* d_in, const int* in_sizes, int n_in,
                              void* d_out, int out_size, void* d_ws, size_t ws_size,
                              hipStream_t stream) {
    const float* theta = (const float*)d_in[0];   // (B,N,D) f32
    const float* gam   = (const float*)d_in[1];   // (B,N,D) f32
    const float* W     = (const float*)d_in[2];   // (B,N,N) f32
    const float* alpha = (const float*)d_in[3];   // (B,N,N) f32
    float* out = (float*)d_out;                   // (B,N,D) f32

    const int totalRows = in_sizes[0] / kD;           // B*N = 8192
    const int nblocks = totalRows / kRowsPerBlock;    // 2048
    const size_t tabEntries = (size_t)kB * kN;        // 8192 float4 per table
    const size_t needWs = 2 * tabEntries * sizeof(float4);   // 256 KB

    if (ws_size >= needWs) {
        float4* sinT = (float4*)d_ws;
        float4* cosT = sinT + tabEntries;
        table_kernel<<<(int)(tabEntries / 256), 256, 0, stream>>>(theta, sinT, cosT);
        kuramoto_kernel<true><<<nblocks, kBlock, 0, stream>>>(
            theta, gam, W, alpha, sinT, cosT, out);
    } else {
        kuramoto_kernel<false><<<nblocks, kBlock, 0, stream>>>(
            theta, gam, W, alpha, nullptr, nullptr, out);
    }
}

// Round 5
// 51.499 us; speedup vs baseline: 3.9653x; 1.3453x over previous
//
#include <hip/hip_runtime.h>
#include <math.h>

constexpr int kN = 4096;
constexpr int kD = 4;
constexpr int kB = 2;
constexpr int kBlock = 256;
constexpr int kRowsPerWave = 4;
constexpr int kWaves = kBlock / 64;                      // 4
constexpr int kRowsPerBlock = kRowsPerWave * kWaves;     // 16
constexpr int kIters = kN / (64 * 4);                    // 16 j-batches (4 j/lane)

// Precompute sin/cos(theta) as float4-per-j tables: sinT[b*N+j] = {s_d0..s_d3}.
__global__ __launch_bounds__(256)
void table_kernel(const float* __restrict__ theta,
                  float4* __restrict__ sinT, float4* __restrict__ cosT)
{
    const int idx = blockIdx.x * blockDim.x + threadIdx.x;   // over B*N
    const float4 t4 = *reinterpret_cast<const float4*>(&theta[(size_t)idx * kD]);
    float4 s4, c4;
    __sincosf(t4.x, &s4.x, &c4.x);
    __sincosf(t4.y, &s4.y, &c4.y);
    __sincosf(t4.z, &s4.z, &c4.z);
    __sincosf(t4.w, &s4.w, &c4.w);
    sinT[idx] = s4;
    cosT[idx] = c4;
}

// 4 rows per wave, no LDS, no barriers; register double-buffered streaming.
template <bool USE_TABLE>
__global__ __launch_bounds__(kBlock)
void kuramoto_kernel(const float* __restrict__ theta,
                     const float* __restrict__ gam,
                     const float* __restrict__ W,
                     const float* __restrict__ alpha,
                     const float4* __restrict__ sinT,
                     const float4* __restrict__ cosT,
                     float* __restrict__ out)
{
    const int tid  = threadIdx.x;
    const int wave = tid >> 6;
    const int lane = tid & 63;

    const int row0 = blockIdx.x * kRowsPerBlock + wave * kRowsPerWave;
    const int b    = row0 >> 12;                          // row0 / kN

    const float* Wr[kRowsPerWave];
    const float* Ar[kRowsPerWave];
    #pragma unroll
    for (int r = 0; r < kRowsPerWave; ++r) {
        Wr[r] = W     + (size_t)(row0 + r) * kN;
        Ar[r] = alpha + (size_t)(row0 + r) * kN;
    }
    const float4* __restrict__ sB = sinT + (size_t)b * kN;
    const float4* __restrict__ cB = cosT + (size_t)b * kN;
    const float* thetaB = theta + (size_t)b * kN * kD;

    float U[kRowsPerWave][kD];
    float V[kRowsPerWave][kD];
    #pragma unroll
    for (int r = 0; r < kRowsPerWave; ++r)
        #pragma unroll
        for (int d = 0; d < kD; ++d) { U[r][d] = 0.f; V[r][d] = 0.f; }

    // One stage: 4 j's per lane (j = k*256 + lane*4 + u), for 4 rows.
    auto load_stage = [&](int k, float4 (&s)[4], float4 (&c)[4],
                          float4 (&w)[4], float4 (&a)[4]) {
        const int jb = k * 256 + lane * 4;
        #pragma unroll
        for (int u = 0; u < 4; ++u) {
            if constexpr (USE_TABLE) {
                s[u] = sB[jb + u];
                c[u] = cB[jb + u];
            } else {
                s[u] = *reinterpret_cast<const float4*>(&thetaB[(size_t)(jb + u) * kD]);
            }
        }
        #pragma unroll
        for (int r = 0; r < kRowsPerWave; ++r) {
            w[r] = *reinterpret_cast<const float4*>(&Wr[r][jb]);
            a[r] = *reinterpret_cast<const float4*>(&Ar[r][jb]);
        }
    };

    auto compute_stage = [&](const float4 (&s)[4], const float4 (&c)[4],
                             const float4 (&w)[4], const float4 (&a)[4]) {
        float sv[4][kD], cv[4][kD];
        #pragma unroll
        for (int u = 0; u < 4; ++u) {
            if constexpr (USE_TABLE) {
                sv[u][0] = s[u].x; sv[u][1] = s[u].y; sv[u][2] = s[u].z; sv[u][3] = s[u].w;
                cv[u][0] = c[u].x; cv[u][1] = c[u].y; cv[u][2] = c[u].z; cv[u][3] = c[u].w;
            } else {
                __sincosf(s[u].x, &sv[u][0], &cv[u][0]);
                __sincosf(s[u].y, &sv[u][1], &cv[u][1]);
                __sincosf(s[u].z, &sv[u][2], &cv[u][2]);
                __sincosf(s[u].w, &sv[u][3], &cv[u][3]);
            }
        }
        #pragma unroll
        for (int r = 0; r < kRowsPerWave; ++r) {
            const float wv[4] = {w[r].x, w[r].y, w[r].z, w[r].w};
            const float av[4] = {a[r].x, a[r].y, a[r].z, a[r].w};
            #pragma unroll
            for (int u = 0; u < 4; ++u) {
                float sa, ca;
                __sincosf(av[u], &sa, &ca);
                const float P = wv[u] * ca;
                const float Q = wv[u] * sa;
                U[r][0] = fmaf(P, sv[u][0], fmaf(-Q, cv[u][0], U[r][0]));
                V[r][0] = fmaf(P, cv[u][0], fmaf( Q, sv[u][0], V[r][0]));
                U[r][1] = fmaf(P, sv[u][1], fmaf(-Q, cv[u][1], U[r][1]));
                V[r][1] = fmaf(P, cv[u][1], fmaf( Q, sv[u][1], V[r][1]));
                U[r][2] = fmaf(P, sv[u][2], fmaf(-Q, cv[u][2], U[r][2]));
                V[r][2] = fmaf(P, cv[u][2], fmaf( Q, sv[u][2], V[r][2]));
                U[r][3] = fmaf(P, sv[u][3], fmaf(-Q, cv[u][3], U[r][3]));
                V[r][3] = fmaf(P, cv[u][3], fmaf( Q, sv[u][3], V[r][3]));
            }
        }
    };

    float4 sA[4], cA[4], wA[4], aA[4];
    float4 sX[4], cX[4], wX[4], aX[4];

    load_stage(0, sA, cA, wA, aA);
    for (int k = 0; k < kIters - 2; k += 2) {
        load_stage(k + 1, sX, cX, wX, aX);
        __builtin_amdgcn_sched_barrier(0);     // keep prefetch above compute
        compute_stage(sA, cA, wA, aA);
        load_stage(k + 2, sA, cA, wA, aA);
        __builtin_amdgcn_sched_barrier(0);
        compute_stage(sX, cX, wX, aX);
    }
    load_stage(kIters - 1, sX, cX, wX, aX);
    __builtin_amdgcn_sched_barrier(0);
    compute_stage(sA, cA, wA, aA);
    compute_stage(sX, cX, wX, aX);

    // Wave-wide butterfly reduction (32 accumulators per wave).
    #pragma unroll
    for (int m = 1; m < 64; m <<= 1) {
        #pragma unroll
        for (int r = 0; r < kRowsPerWave; ++r)
            #pragma unroll
            for (int d = 0; d < kD; ++d) {
                U[r][d] += __shfl_xor(U[r][d], m, 64);
                V[r][d] += __shfl_xor(V[r][d], m, 64);
            }
    }

    // Lane r writes row row0+r (constant register indices only).
    #pragma unroll
    for (int r = 0; r < kRowsPerWave; ++r) {
        if (lane == r) {
            const int row = row0 + r;
            const float4 t4 = *reinterpret_cast<const float4*>(&theta[(size_t)row * kD]);
            const float4 g4 = *reinterpret_cast<const float4*>(&gam[(size_t)row * kD]);
            const float tv[4] = {t4.x, t4.y, t4.z, t4.w};
            const float gv[4] = {g4.x, g4.y, g4.z, g4.w};
            constexpr float scale = 1.0f / (float)kN;     // GLOBAL_COUPLING / N
            float x[4];
            float nsq = 0.f;
            #pragma unroll
            for (int d = 0; d < kD; ++d) {
                float si, ci;
                __sincosf(tv[d], &si, &ci);
                const float coup = scale * (ci * U[r][d] - si * V[r][d]);
                x[d] = gv[d] + coup;      // gamma + coupling (drive cancels theta)
                nsq += x[d] * x[d];
            }
            const float inv = 1.0f / fmaxf(sqrtf(nsq), 1e-6f);
            float4 o;
            o.x = x[0] * inv; o.y = x[1] * inv; o.z = x[2] * inv; o.w = x[3] * inv;
            *reinterpret_cast<float4*>(&out[(size_t)row * kD]) = o;
        }
    }
}

extern "C" void kernel_launch(void* const* d_in, const int* in_sizes, int n_in,
                              void* d_out, int out_size, void* d_ws, size_t ws_size,
                              hipStream_t stream) {
    const float* theta = (const float*)d_in[0];   // (B,N,D) f32
    const float* gam   = (const float*)d_in[1];   // (B,N,D) f32
    const float* W     = (const float*)d_in[2];   // (B,N,N) f32
    const float* alpha = (const float*)d_in[3];   // (B,N,N) f32
    float* out = (float*)d_out;                   // (B,N,D) f32

    const int totalRows = in_sizes[0] / kD;           // B*N = 8192
    const int nblocks = totalRows / kRowsPerBlock;    // 512
    const size_t tabEntries = (size_t)kB * kN;        // 8192 float4 per table
    const size_t needWs = 2 * tabEntries * sizeof(float4);   // 256 KB

    if (ws_size >= needWs) {
        float4* sinT = (float4*)d_ws;
        float4* cosT = sinT + tabEntries;
        table_kernel<<<(int)(tabEntries / 256), 256, 0, stream>>>(theta, sinT, cosT);
        kuramoto_kernel<true><<<nblocks, kBlock, 0, stream>>>(
            theta, gam, W, alpha, sinT, cosT, out);
    } else {
        kuramoto_kernel<false><<<nblocks, kBlock, 0, stream>>>(
            theta, gam, W, alpha, nullptr, nullptr, out);
    }
}